// Round 6
// baseline (906.238 us; speedup 1.0000x reference)
//
#include <hip/hip_runtime.h>
#include <hip/hip_bf16.h>

typedef __attribute__((ext_vector_type(8))) short bf16x8;
typedef __attribute__((ext_vector_type(16))) float f32x16;
typedef __attribute__((ext_vector_type(4))) unsigned int uint4v;
typedef unsigned short ushort_t;
typedef unsigned int uint_t;

#define N_NODES 16384
#define HD 128
#define NOUT 384
#define BT_K 16640            // 16384 + 128 + 128
#define LSTR 136              // LDS row stride in shorts (68 dwords = 4 mod 32: conflict-free, measured)

static __device__ __forceinline__ ushort_t f2bf(float f) {
  __hip_bfloat16 b = __float2bfloat16(f);
  return *reinterpret_cast<ushort_t*>(&b);
}

// ---------------- fused prep ----------------
__global__ void prep_all(const float* __restrict__ A, const float* __restrict__ U1,
                         const float* __restrict__ U2, const float* __restrict__ nh,
                         ushort_t* __restrict__ Bt, ushort_t* __restrict__ h1,
                         ushort_t* __restrict__ h2, ushort_t* __restrict__ h1t) {
  __shared__ float sm[64][65];
  const int b = blockIdx.x;
  const int t = threadIdx.x;
  const int tx = t & 63, ty = t >> 6;
  if (b < 1536) {
    const int kt = b & 255, nt = b >> 8;
    const int k0 = kt * 64, n0 = nt * 64;
#pragma unroll
    for (int s = 0; s < 16; ++s) {
      int kk = ty + s * 4;
      sm[kk][tx] = A[(size_t)(k0 + kk) * NOUT + n0 + tx];
    }
    __syncthreads();
#pragma unroll
    for (int s = 0; s < 16; ++s) {
      int nn = ty + s * 4;
      Bt[(size_t)(n0 + nn) * BT_K + k0 + tx] = f2bf(sm[tx][nn]);
    }
  } else if (b < 1728) {
    int idx = (b - 1536) * 256 + t;   // 0..49151
    int n = idx >> 7, i = idx & 127;
    Bt[(size_t)n * BT_K + 16384 + i] = f2bf(U1[idx]);
    Bt[(size_t)n * BT_K + 16512 + i] = f2bf(U2[idx]);
  } else {
    const int g = b - 1728;           // 0..511
    const int mt = g & 255, jt = g >> 8;
    const int m0 = mt * 64, j0 = jt * 64;
#pragma unroll
    for (int s = 0; s < 16; ++s) {
      int mm = ty + s * 4;
      float f1 = nh[(size_t)(m0 + mm) * 256 + j0 + tx];
      float f2 = nh[(size_t)(m0 + mm) * 256 + 128 + j0 + tx];
      h1[(size_t)(m0 + mm) * HD + j0 + tx] = f2bf(f1);
      h2[(size_t)(m0 + mm) * HD + j0 + tx] = f2bf(f2);
      sm[mm][tx] = f1;
    }
    __syncthreads();
#pragma unroll
    for (int s = 0; s < 16; ++s) {
      int jj = ty + s * 4;
      h1t[(size_t)(j0 + jj) * N_NODES + m0 + tx] = f2bf(sm[tx][jj]);
    }
  }
}

// ---------------- main GEMM, split-K x4: out[m][n] += sum_{k in chunk} X[m,k]*Bt[n,k] ----------------
// X[m, i*128+j] = h1[m,i]*h2[m,j] for i<128; X[m,16384+i]=h1[m,i]; X[m,16512+j]=h2[m,j]
// grid = 128 Mt x 3 Nt x 4 ks; ks chunk = slices [ks*32, ks*32+32); ks==3 also does U tails.
// bias folded into ks==0 accumulator init; partials merged with f32 atomicAdd onto zeroed out.
__global__ __launch_bounds__(256)
void gemm_kernel(const ushort_t* __restrict__ Bt, const ushort_t* __restrict__ h1bf,
                 const ushort_t* __restrict__ h2bf, const ushort_t* __restrict__ h1t,
                 const float* __restrict__ u2b, float* __restrict__ out) {
  __shared__ short bsh[128 * LSTR];   // B tile [n][k128], padded
  const int tid = threadIdx.x;
  const int bid = blockIdx.x;
  const int ks = bid & 3;             // K-chunk
  const int mn = bid >> 2;
  const int Nt = mn % 3, Mt = mn / 3;
  const int n0 = Nt * 128, m0 = Mt * 128;
  const int lane = tid & 63, wv = tid >> 6;
  const int l31 = lane & 31, oct = lane >> 5;
  const int wm = wv >> 1, wn = wv & 1;           // 2x2 wave grid
  const int mbase = m0 + wm * 64;
  const int nbase_l = wn * 64;

  const int k_begin = ks * 32;
  const int k_end = (ks == 3) ? 130 : k_begin + 32;   // ks==3: 96..129 incl. U1/U2 tails
  const int h_end = (ks == 3) ? 128 : k_end;

  // resident h2 A-fragments: rows mbase+ms*32+l31, k2 = c*16 + oct*8 + [0..8)
  uint4v h2u[2][8];
#pragma unroll
  for (int ms = 0; ms < 2; ++ms) {
    const ushort_t* hp = h2bf + (size_t)(mbase + ms * 32 + l31) * HD + oct * 8;
#pragma unroll
    for (int c = 0; c < 8; ++c)
      h2u[ms][c] = *reinterpret_cast<const uint4v*>(hp + c * 16);
  }

  // acc init: bias for ks==0 (col = lane&31 is the same for all 16 regs), else 0
  f32x16 acc[2][2];
  {
    float bb0 = (ks == 0) ? u2b[n0 + nbase_l + l31] : 0.0f;
    float bb1 = (ks == 0) ? u2b[n0 + nbase_l + 32 + l31] : 0.0f;
#pragma unroll
    for (int ms = 0; ms < 2; ++ms) {
      acc[ms][0] = (f32x16)(bb0);
      acc[ms][1] = (f32x16)(bb1);
    }
  }

  // staging: 32 KB tile in two 16 KB halves through one breg[4] (16 VGPRs).
  const int prow = tid >> 4;          // 0..15
  const int poff = tid & 15;          // *16 B
  uint4 breg[4];
  auto load_half = [&](int it, int h) {
#pragma unroll
    for (int l = 0; l < 4; ++l) {
      int row = h * 64 + l * 16 + prow;
      breg[l] = *reinterpret_cast<const uint4*>(
          Bt + (size_t)(n0 + row) * BT_K + (size_t)it * 128 + poff * 8);
    }
  };
  auto write_half = [&](int h) {
#pragma unroll
    for (int l = 0; l < 4; ++l) {
      int row = h * 64 + l * 16 + prow;
      *reinterpret_cast<uint4*>(&bsh[row * LSTR + poff * 8]) = breg[l];
    }
  };

  load_half(k_begin, 0);   // prologue

  // h1 scalar rolling prefetch (one per ms-row)
  const int hrow0 = mbase + l31;
  const int hrow1 = mbase + 32 + l31;
  ushort_t hn0 = (k_begin < 128) ? h1t[(size_t)k_begin * N_NODES + hrow0] : (ushort_t)0;
  ushort_t hn1 = (k_begin < 128) ? h1t[(size_t)k_begin * N_NODES + hrow1] : (ushort_t)0;

  for (int it = k_begin; it < k_end; ++it) {
    write_half(0);
    load_half(it, 1);
    write_half(1);
    __syncthreads();
    if (it + 1 < k_end) load_half(it + 1, 0);   // in flight across this tile's compute

    if (it < 128) {
      float h1f0 = __uint_as_float((uint_t)hn0 << 16);
      float h1f1 = __uint_as_float((uint_t)hn1 << 16);
      if (it + 1 < h_end) {
        hn0 = h1t[(size_t)(it + 1) * N_NODES + hrow0];
        hn1 = h1t[(size_t)(it + 1) * N_NODES + hrow1];
      }
#pragma unroll
      for (int c = 0; c < 8; ++c) {
        bf16x8 b0 = *reinterpret_cast<const bf16x8*>(&bsh[(nbase_l + l31) * LSTR + c * 16 + oct * 8]);
        bf16x8 b1 = *reinterpret_cast<const bf16x8*>(&bsh[(nbase_l + 32 + l31) * LSTR + c * 16 + oct * 8]);
#pragma unroll
        for (int ms = 0; ms < 2; ++ms) {
          const float hf = ms ? h1f1 : h1f0;
          uint4v avu;
#pragma unroll
          for (int r = 0; r < 4; ++r) {
            uint_t u = h2u[ms][c][r];
            float lo = __uint_as_float(u << 16);
            float hi = __uint_as_float(u & 0xffff0000u);
            avu[r] = __builtin_amdgcn_perm(__float_as_uint(hi * hf), __float_as_uint(lo * hf),
                                           0x07060302u);
          }
          bf16x8 av = __builtin_bit_cast(bf16x8, avu);
          acc[ms][0] = __builtin_amdgcn_mfma_f32_32x32x16_bf16(av, b0, acc[ms][0], 0, 0, 0);
          acc[ms][1] = __builtin_amdgcn_mfma_f32_32x32x16_bf16(av, b1, acc[ms][1], 0, 0, 0);
        }
      }
    } else if (it == 128) {
      // A-fragment = h1 directly (linear U1 term)
#pragma unroll
      for (int c = 0; c < 8; ++c) {
        bf16x8 b0 = *reinterpret_cast<const bf16x8*>(&bsh[(nbase_l + l31) * LSTR + c * 16 + oct * 8]);
        bf16x8 b1 = *reinterpret_cast<const bf16x8*>(&bsh[(nbase_l + 32 + l31) * LSTR + c * 16 + oct * 8]);
#pragma unroll
        for (int ms = 0; ms < 2; ++ms) {
          bf16x8 a = *reinterpret_cast<const bf16x8*>(
              h1bf + (size_t)(mbase + ms * 32 + l31) * HD + c * 16 + oct * 8);
          acc[ms][0] = __builtin_amdgcn_mfma_f32_32x32x16_bf16(a, b0, acc[ms][0], 0, 0, 0);
          acc[ms][1] = __builtin_amdgcn_mfma_f32_32x32x16_bf16(a, b1, acc[ms][1], 0, 0, 0);
        }
      }
    } else {
      // A-fragment = h2 (linear U2 term), already resident
#pragma unroll
      for (int c = 0; c < 8; ++c) {
        bf16x8 b0 = *reinterpret_cast<const bf16x8*>(&bsh[(nbase_l + l31) * LSTR + c * 16 + oct * 8]);
        bf16x8 b1 = *reinterpret_cast<const bf16x8*>(&bsh[(nbase_l + 32 + l31) * LSTR + c * 16 + oct * 8]);
#pragma unroll
        for (int ms = 0; ms < 2; ++ms) {
          bf16x8 a = __builtin_bit_cast(bf16x8, h2u[ms][c]);
          acc[ms][0] = __builtin_amdgcn_mfma_f32_32x32x16_bf16(a, b0, acc[ms][0], 0, 0, 0);
          acc[ms][1] = __builtin_amdgcn_mfma_f32_32x32x16_bf16(a, b1, acc[ms][1], 0, 0, 0);
        }
      }
    }
    __syncthreads();
  }

  // epilogue: merge partial via device-scope f32 atomics (out pre-zeroed).
  // C/D: col = lane&31, row = (reg&3) + 8*(reg>>2) + 4*oct
#pragma unroll
  for (int ns = 0; ns < 2; ++ns) {
    int col = n0 + nbase_l + ns * 32 + l31;
#pragma unroll
    for (int ms = 0; ms < 2; ++ms) {
#pragma unroll
      for (int r = 0; r < 16; ++r) {
        int row = (r & 3) + 8 * (r >> 2) + 4 * oct;
        int m = mbase + ms * 32 + row;
        atomicAdd(&out[(size_t)m * NOUT + col], acc[ms][ns][r]);
      }
    }
  }
}

extern "C" void kernel_launch(void* const* d_in, const int* in_sizes, int n_in,
                              void* d_out, int out_size, void* d_ws, size_t ws_size,
                              hipStream_t stream) {
  const float* nh  = (const float*)d_in[0];   // (16384, 2, 128)
  const float* A   = (const float*)d_in[1];   // (128, 128, 384)
  const float* U1  = (const float*)d_in[2];   // (384, 128)
  const float* U2  = (const float*)d_in[3];   // (384, 128)
  const float* U2b = (const float*)d_in[4];   // (384,)

  char* ws = (char*)d_ws;
  ushort_t* Bt   = (ushort_t*)(ws);                 // 384*16640*2  = 12,779,520
  ushort_t* h1bf = (ushort_t*)(ws + 12779520);      // 16384*128*2 =  4,194,304
  ushort_t* h2bf = (ushort_t*)(ws + 16973824);      //               4,194,304
  ushort_t* h1t  = (ushort_t*)(ws + 21168128);      //               4,194,304

  hipMemsetAsync(d_out, 0, (size_t)out_size * sizeof(float), stream);
  prep_all<<<dim3(2240), 256, 0, stream>>>(A, U1, U2, nh, Bt, h1bf, h2bf, h1t);
  gemm_kernel<<<dim3(1536), 256, 0, stream>>>(Bt, h1bf, h2bf, h1t, U2b, (float*)d_out);
}

// Round 7
// 647.991 us; speedup vs baseline: 1.3985x; 1.3985x over previous
//
#include <hip/hip_runtime.h>
#include <hip/hip_bf16.h>

typedef __attribute__((ext_vector_type(8))) short bf16x8;
typedef __attribute__((ext_vector_type(16))) float f32x16;
typedef __attribute__((ext_vector_type(4))) unsigned int uint4v;
typedef unsigned short ushort_t;
typedef unsigned int uint_t;

#define N_NODES 16384
#define HD 128
#define NOUT 384
// packed B: pk[it][g][c][oct][l31][j]  it:0..129 (128,129 = U1,U2 tails)
//   g = n>>5 (12 groups), c = (k2>>4)&7, oct = (k2>>3)&1, j = k2&7, l31 = n&31
//   byte offset = ((it*12+g)*16 + c*2 + oct)*512 + l31*16 + j*2 ; per-it = 98304 B

static __device__ __forceinline__ ushort_t f2bf(float f) {
  __hip_bfloat16 b = __float2bfloat16(f);
  return *reinterpret_cast<ushort_t*>(&b);
}

// ---------------- fused prep (384 threads/block) ----------------
// b in [0,256): A-pack. it = b>>1, half = b&1 -> k rows [it*128+half*64, +64)
// b in [256,260): U-pack. u = (b-256)>>1, half = b&1 -> it = 128+u
// b in [260,772): h-prep (uses threads 0..255 only)
__global__ void prep_all(const float* __restrict__ A, const float* __restrict__ U1,
                         const float* __restrict__ U2, const float* __restrict__ nh,
                         ushort_t* __restrict__ pk, ushort_t* __restrict__ h1,
                         ushort_t* __restrict__ h2, ushort_t* __restrict__ h1t) {
  __shared__ __align__(16) char smem[49152];
  const int b = blockIdx.x;
  const int t = threadIdx.x;

  if (b < 260) {
    short* spk = reinterpret_cast<short*>(smem);
    const int half = b & 1;
    const int gg = t >> 5, ll = t & 31;
    if (b < 256) {
      const int it = b >> 1;
      const size_t krow0 = (size_t)it * 128 + half * 64;
#pragma unroll 4
      for (int kl = 0; kl < 64; ++kl) {
        float v = A[(krow0 + kl) * NOUT + t];
        int cl = kl >> 4, oc = (kl >> 3) & 1, j = kl & 7;
        spk[(gg * 8 + cl * 2 + oc) * 256 + ll * 8 + j] = f2bf(v);
      }
    } else {
      const int u = (b - 256) >> 1;
      const float* U = u ? U2 : U1;
#pragma unroll 4
      for (int kl = 0; kl < 64; ++kl) {
        float v = U[(size_t)t * HD + half * 64 + kl];
        int cl = kl >> 4, oc = (kl >> 3) & 1, j = kl & 7;
        spk[(gg * 8 + cl * 2 + oc) * 256 + ll * 8 + j] = f2bf(v);
      }
    }
    __syncthreads();
    // dump 48 KB: thread t -> 64 shorts at flat f = t*64
    const int it_out = (b < 256) ? (b >> 1) : (128 + ((b - 256) >> 1));
    const int f = t * 64;
    const int g = f >> 11;             // 2048 shorts per (g) chunk in this half
    const int inner = f & 2047;
    ushort_t* dst = pk + (size_t)it_out * 49152 + g * 4096 + half * 2048 + inner;
    const uint4* src = reinterpret_cast<const uint4*>(spk + f);
    uint4* d4 = reinterpret_cast<uint4*>(dst);
#pragma unroll
    for (int q = 0; q < 8; ++q) d4[q] = src[q];
  } else {
    if (t < 256) {
      float (*sm)[65] = reinterpret_cast<float(*)[65]>(smem);
      const int g = b - 260;            // 0..511
      const int mt = g & 255, jt = g >> 8;
      const int tx = t & 63, ty = t >> 6;
      const int m0 = mt * 64, j0 = jt * 64;
#pragma unroll
      for (int s = 0; s < 16; ++s) {
        int mm = ty + s * 4;
        float f1 = nh[(size_t)(m0 + mm) * 256 + j0 + tx];
        float f2 = nh[(size_t)(m0 + mm) * 256 + 128 + j0 + tx];
        h1[(size_t)(m0 + mm) * HD + j0 + tx] = f2bf(f1);
        h2[(size_t)(m0 + mm) * HD + j0 + tx] = f2bf(f2);
        sm[mm][tx] = f1;
      }
      __syncthreads();
#pragma unroll
      for (int s = 0; s < 16; ++s) {
        int jj = ty + s * 4;
        h1t[(size_t)(j0 + jj) * N_NODES + m0 + tx] = f2bf(sm[tx][jj]);
      }
    }
  }
}

// ---------------- main GEMM: barrier-free, LDS-free ----------------
// out[m][n] (+=) sum_k X[m,k]*B[k,n]; X[m,i*128+j]=h1[m,i]*h2[m,j] (i<128),
// tails: it=128 -> A=h1 (U1 term), it=129 -> A=h2 (U2 term).
// grid = 128 Mt x 3 Nt x 2 ks. ks=0: it 0..63; ks=1: it 64..129 (+bias init).
// Partials merged with device-scope f32 atomicAdd onto zeroed out.
__global__ __launch_bounds__(256)
void gemm_kernel(const ushort_t* __restrict__ pk, const ushort_t* __restrict__ h1bf,
                 const ushort_t* __restrict__ h2bf, const ushort_t* __restrict__ h1t,
                 const float* __restrict__ u2b, float* __restrict__ out) {
  const int tid = threadIdx.x;
  const int bid = blockIdx.x;
  const int ks = bid & 1;
  const int mn = bid >> 1;
  const int Nt = mn % 3, Mt = mn / 3;
  const int n0 = Nt * 128, m0 = Mt * 128;
  const int lane = tid & 63, wv = tid >> 6;
  const int l31 = lane & 31, oct = lane >> 5;
  const int wm = wv >> 1, wn = wv & 1;           // 2x2 wave grid
  const int mbase = m0 + wm * 64;
  const int nbase_l = wn * 64;

  const int k_begin = ks ? 64 : 0;
  const int k_end   = ks ? 130 : 64;

  // B fragment pointers: byte off = ((it*12+g)*16 + c*2 + oct)*512 + l31*16
  const int g0 = Nt * 4 + wn * 2;
  const char* pkb = reinterpret_cast<const char*>(pk);
  const char* b0base = pkb + (size_t)(g0 * 16 + oct) * 512 + (size_t)l31 * 16;

  // resident h2 A-fragments: rows mbase+ms*32+l31, k2 = c*16 + oct*8 + [0..8)
  uint4v h2u[2][8];
#pragma unroll
  for (int ms = 0; ms < 2; ++ms) {
    const ushort_t* hp = h2bf + (size_t)(mbase + ms * 32 + l31) * HD + oct * 8;
#pragma unroll
    for (int c = 0; c < 8; ++c)
      h2u[ms][c] = *reinterpret_cast<const uint4v*>(hp + c * 16);
  }

  // acc init: bias on ks==1 (col = lane&31 identical for all 16 regs), else 0
  f32x16 acc[2][2];
  {
    float bb0 = ks ? u2b[n0 + nbase_l + l31] : 0.0f;
    float bb1 = ks ? u2b[n0 + nbase_l + 32 + l31] : 0.0f;
#pragma unroll
    for (int ms = 0; ms < 2; ++ms) {
      acc[ms][0] = (f32x16)(bb0);
      acc[ms][1] = (f32x16)(bb1);
    }
  }

  // h1 scalar rolling prefetch
  const int hrow0 = mbase + l31;
  const int hrow1 = mbase + 32 + l31;
  ushort_t hn0 = h1t[(size_t)k_begin * N_NODES + hrow0];
  ushort_t hn1 = h1t[(size_t)k_begin * N_NODES + hrow1];

  for (int it = k_begin; it < k_end; ++it) {
    const char* bit = b0base + (size_t)it * 98304;
    if (it < 128) {
      float h1f0 = __uint_as_float((uint_t)hn0 << 16);
      float h1f1 = __uint_as_float((uint_t)hn1 << 16);
      if (it + 1 < 128) {
        hn0 = h1t[(size_t)(it + 1) * N_NODES + hrow0];
        hn1 = h1t[(size_t)(it + 1) * N_NODES + hrow1];
      }
#pragma unroll
      for (int c = 0; c < 8; ++c) {
        uint4v bv0 = *reinterpret_cast<const uint4v*>(bit + c * 1024);
        uint4v bv1 = *reinterpret_cast<const uint4v*>(bit + 8192 + c * 1024);
        bf16x8 b0 = __builtin_bit_cast(bf16x8, bv0);
        bf16x8 b1 = __builtin_bit_cast(bf16x8, bv1);
#pragma unroll
        for (int ms = 0; ms < 2; ++ms) {
          const float hf = ms ? h1f1 : h1f0;
          uint4v avu;
#pragma unroll
          for (int r = 0; r < 4; ++r) {
            uint_t u = h2u[ms][c][r];
            float lo = __uint_as_float(u << 16);
            float hi = __uint_as_float(u & 0xffff0000u);
            avu[r] = __builtin_amdgcn_perm(__float_as_uint(hi * hf), __float_as_uint(lo * hf),
                                           0x07060302u);
          }
          bf16x8 av = __builtin_bit_cast(bf16x8, avu);
          acc[ms][0] = __builtin_amdgcn_mfma_f32_32x32x16_bf16(av, b0, acc[ms][0], 0, 0, 0);
          acc[ms][1] = __builtin_amdgcn_mfma_f32_32x32x16_bf16(av, b1, acc[ms][1], 0, 0, 0);
        }
      }
    } else if (it == 128) {
      // U1 term: A-fragment = h1 (m-major)
#pragma unroll
      for (int c = 0; c < 8; ++c) {
        uint4v bv0 = *reinterpret_cast<const uint4v*>(bit + c * 1024);
        uint4v bv1 = *reinterpret_cast<const uint4v*>(bit + 8192 + c * 1024);
        bf16x8 b0 = __builtin_bit_cast(bf16x8, bv0);
        bf16x8 b1 = __builtin_bit_cast(bf16x8, bv1);
#pragma unroll
        for (int ms = 0; ms < 2; ++ms) {
          bf16x8 a = *reinterpret_cast<const bf16x8*>(
              h1bf + (size_t)(mbase + ms * 32 + l31) * HD + c * 16 + oct * 8);
          acc[ms][0] = __builtin_amdgcn_mfma_f32_32x32x16_bf16(a, b0, acc[ms][0], 0, 0, 0);
          acc[ms][1] = __builtin_amdgcn_mfma_f32_32x32x16_bf16(a, b1, acc[ms][1], 0, 0, 0);
        }
      }
    } else {
      // U2 term: A-fragment = h2 (resident)
#pragma unroll
      for (int c = 0; c < 8; ++c) {
        uint4v bv0 = *reinterpret_cast<const uint4v*>(bit + c * 1024);
        uint4v bv1 = *reinterpret_cast<const uint4v*>(bit + 8192 + c * 1024);
        bf16x8 b0 = __builtin_bit_cast(bf16x8, bv0);
        bf16x8 b1 = __builtin_bit_cast(bf16x8, bv1);
#pragma unroll
        for (int ms = 0; ms < 2; ++ms) {
          bf16x8 a = __builtin_bit_cast(bf16x8, h2u[ms][c]);
          acc[ms][0] = __builtin_amdgcn_mfma_f32_32x32x16_bf16(a, b0, acc[ms][0], 0, 0, 0);
          acc[ms][1] = __builtin_amdgcn_mfma_f32_32x32x16_bf16(a, b1, acc[ms][1], 0, 0, 0);
        }
      }
    }
  }

  // epilogue: merge partial via device-scope f32 atomics (out pre-zeroed).
  // C/D: col = lane&31, row = (reg&3) + 8*(reg>>2) + 4*oct
#pragma unroll
  for (int ns = 0; ns < 2; ++ns) {
    int col = n0 + nbase_l + ns * 32 + l31;
#pragma unroll
    for (int ms = 0; ms < 2; ++ms) {
#pragma unroll
      for (int r = 0; r < 16; ++r) {
        int row = (r & 3) + 8 * (r >> 2) + 4 * oct;
        int m = mbase + ms * 32 + row;
        atomicAdd(&out[(size_t)m * NOUT + col], acc[ms][ns][r]);
      }
    }
  }
}

extern "C" void kernel_launch(void* const* d_in, const int* in_sizes, int n_in,
                              void* d_out, int out_size, void* d_ws, size_t ws_size,
                              hipStream_t stream) {
  const float* nh  = (const float*)d_in[0];   // (16384, 2, 128)
  const float* A   = (const float*)d_in[1];   // (128, 128, 384)
  const float* U1  = (const float*)d_in[2];   // (384, 128)
  const float* U2  = (const float*)d_in[3];   // (384, 128)
  const float* U2b = (const float*)d_in[4];   // (384,)

  char* ws = (char*)d_ws;
  ushort_t* pk   = (ushort_t*)(ws);                 // 130*98304    = 12,779,520 B
  ushort_t* h1bf = (ushort_t*)(ws + 12779520);      // 16384*128*2 =  4,194,304
  ushort_t* h2bf = (ushort_t*)(ws + 16973824);      //               4,194,304
  ushort_t* h1t  = (ushort_t*)(ws + 21168128);      //               4,194,304

  hipMemsetAsync(d_out, 0, (size_t)out_size * sizeof(float), stream);
  prep_all<<<dim3(772), 384, 0, stream>>>(A, U1, U2, nh, pk, h1bf, h2bf, h1t);
  gemm_kernel<<<dim3(768), 256, 0, stream>>>(pk, h1bf, h2bf, h1t, U2b, (float*)d_out);
}

// Round 8
// 642.178 us; speedup vs baseline: 1.4112x; 1.0091x over previous
//
#include <hip/hip_runtime.h>
#include <hip/hip_bf16.h>

typedef __attribute__((ext_vector_type(8))) short bf16x8;
typedef __attribute__((ext_vector_type(16))) float f32x16;
typedef __attribute__((ext_vector_type(4))) unsigned int uint4v;
typedef unsigned short ushort_t;
typedef unsigned int uint_t;

#define N_NODES 16384
#define HD 128
#define NOUT 384
#define PART_ELEMS 6291456    // 16384*384
// packed B: pk[it][g][c][oct][l31][j]  it:0..129 (128,129 = U1,U2 tails)
//   byte offset = ((it*12+g)*16 + c*2 + oct)*512 + l31*16 + j*2 ; per-it = 98304 B

static __device__ __forceinline__ ushort_t f2bf(float f) {
  __hip_bfloat16 b = __float2bfloat16(f);
  return *reinterpret_cast<ushort_t*>(&b);
}

// ---------------- fused prep (384 threads/block) ----------------
__global__ void prep_all(const float* __restrict__ A, const float* __restrict__ U1,
                         const float* __restrict__ U2, const float* __restrict__ nh,
                         ushort_t* __restrict__ pk, ushort_t* __restrict__ h1,
                         ushort_t* __restrict__ h2, ushort_t* __restrict__ h1t) {
  __shared__ __align__(16) char smem[49152];
  const int b = blockIdx.x;
  const int t = threadIdx.x;

  if (b < 260) {
    short* spk = reinterpret_cast<short*>(smem);
    const int half = b & 1;
    const int gg = t >> 5, ll = t & 31;
    if (b < 256) {
      const int it = b >> 1;
      const size_t krow0 = (size_t)it * 128 + half * 64;
#pragma unroll 4
      for (int kl = 0; kl < 64; ++kl) {
        float v = A[(krow0 + kl) * NOUT + t];
        int cl = kl >> 4, oc = (kl >> 3) & 1, j = kl & 7;
        spk[(gg * 8 + cl * 2 + oc) * 256 + ll * 8 + j] = f2bf(v);
      }
    } else {
      const int u = (b - 256) >> 1;
      const float* U = u ? U2 : U1;
#pragma unroll 4
      for (int kl = 0; kl < 64; ++kl) {
        float v = U[(size_t)t * HD + half * 64 + kl];
        int cl = kl >> 4, oc = (kl >> 3) & 1, j = kl & 7;
        spk[(gg * 8 + cl * 2 + oc) * 256 + ll * 8 + j] = f2bf(v);
      }
    }
    __syncthreads();
    const int it_out = (b < 256) ? (b >> 1) : (128 + ((b - 256) >> 1));
    const int f = t * 64;
    const int g = f >> 11;
    const int inner = f & 2047;
    ushort_t* dst = pk + (size_t)it_out * 49152 + g * 4096 + half * 2048 + inner;
    const uint4* src = reinterpret_cast<const uint4*>(spk + f);
    uint4* d4 = reinterpret_cast<uint4*>(dst);
#pragma unroll
    for (int q = 0; q < 8; ++q) d4[q] = src[q];
  } else {
    if (t < 256) {
      float (*sm)[65] = reinterpret_cast<float(*)[65]>(smem);
      const int g = b - 260;            // 0..511
      const int mt = g & 255, jt = g >> 8;
      const int tx = t & 63, ty = t >> 6;
      const int m0 = mt * 64, j0 = jt * 64;
#pragma unroll
      for (int s = 0; s < 16; ++s) {
        int mm = ty + s * 4;
        float f1 = nh[(size_t)(m0 + mm) * 256 + j0 + tx];
        float f2 = nh[(size_t)(m0 + mm) * 256 + 128 + j0 + tx];
        h1[(size_t)(m0 + mm) * HD + j0 + tx] = f2bf(f1);
        h2[(size_t)(m0 + mm) * HD + j0 + tx] = f2bf(f2);
        sm[mm][tx] = f1;
      }
      __syncthreads();
#pragma unroll
      for (int s = 0; s < 16; ++s) {
        int jj = ty + s * 4;
        h1t[(size_t)(j0 + jj) * N_NODES + m0 + tx] = f2bf(sm[tx][jj]);
      }
    }
  }
}

// ---------------- main GEMM: barrier-free, LDS-free, atomic-free ----------------
// grid = 128 Mt x 3 Nt x 2 ks. ks=0: it 0..63 -> part[0]; ks=1: it 64..129 (+bias) -> part[1].
__global__ __launch_bounds__(256)
void gemm_kernel(const ushort_t* __restrict__ pk, const ushort_t* __restrict__ h1bf,
                 const ushort_t* __restrict__ h2bf, const ushort_t* __restrict__ h1t,
                 const float* __restrict__ u2b, float* __restrict__ part) {
  const int tid = threadIdx.x;
  const int bid = blockIdx.x;
  const int ks = bid & 1;
  const int mn = bid >> 1;
  const int Nt = mn % 3, Mt = mn / 3;
  const int n0 = Nt * 128, m0 = Mt * 128;
  const int lane = tid & 63, wv = tid >> 6;
  const int l31 = lane & 31, oct = lane >> 5;
  const int wm = wv >> 1, wn = wv & 1;           // 2x2 wave grid
  const int mbase = m0 + wm * 64;
  const int nbase_l = wn * 64;

  const int k_begin = ks ? 64 : 0;
  const int k_end   = ks ? 130 : 64;

  const int g0 = Nt * 4 + wn * 2;
  const char* pkb = reinterpret_cast<const char*>(pk);
  const char* b0base = pkb + (size_t)(g0 * 16 + oct) * 512 + (size_t)l31 * 16;

  // resident h2 A-fragments: rows mbase+ms*32+l31, k2 = c*16 + oct*8 + [0..8)
  uint4v h2u[2][8];
#pragma unroll
  for (int ms = 0; ms < 2; ++ms) {
    const ushort_t* hp = h2bf + (size_t)(mbase + ms * 32 + l31) * HD + oct * 8;
#pragma unroll
    for (int c = 0; c < 8; ++c)
      h2u[ms][c] = *reinterpret_cast<const uint4v*>(hp + c * 16);
  }

  // acc init: bias on ks==1 (col = lane&31 identical for all 16 regs), else 0
  f32x16 acc[2][2];
  {
    float bb0 = ks ? u2b[n0 + nbase_l + l31] : 0.0f;
    float bb1 = ks ? u2b[n0 + nbase_l + 32 + l31] : 0.0f;
#pragma unroll
    for (int ms = 0; ms < 2; ++ms) {
      acc[ms][0] = (f32x16)(bb0);
      acc[ms][1] = (f32x16)(bb1);
    }
  }

  // h1 scalar rolling prefetch
  const int hrow0 = mbase + l31;
  const int hrow1 = mbase + 32 + l31;
  ushort_t hn0 = h1t[(size_t)k_begin * N_NODES + hrow0];
  ushort_t hn1 = h1t[(size_t)k_begin * N_NODES + hrow1];

  for (int it = k_begin; it < k_end; ++it) {
    const char* bit = b0base + (size_t)it * 98304;
    if (it < 128) {
      float h1f0 = __uint_as_float((uint_t)hn0 << 16);
      float h1f1 = __uint_as_float((uint_t)hn1 << 16);
      if (it + 1 < 128) {
        hn0 = h1t[(size_t)(it + 1) * N_NODES + hrow0];
        hn1 = h1t[(size_t)(it + 1) * N_NODES + hrow1];
      }
#pragma unroll
      for (int c = 0; c < 8; ++c) {
        uint4v bv0 = *reinterpret_cast<const uint4v*>(bit + c * 1024);
        uint4v bv1 = *reinterpret_cast<const uint4v*>(bit + 8192 + c * 1024);
        bf16x8 b0 = __builtin_bit_cast(bf16x8, bv0);
        bf16x8 b1 = __builtin_bit_cast(bf16x8, bv1);
#pragma unroll
        for (int ms = 0; ms < 2; ++ms) {
          const float hf = ms ? h1f1 : h1f0;
          uint4v avu;
#pragma unroll
          for (int r = 0; r < 4; ++r) {
            uint_t u = h2u[ms][c][r];
            float lo = __uint_as_float(u << 16);
            float hi = __uint_as_float(u & 0xffff0000u);
            avu[r] = __builtin_amdgcn_perm(__float_as_uint(hi * hf), __float_as_uint(lo * hf),
                                           0x07060302u);
          }
          bf16x8 av = __builtin_bit_cast(bf16x8, avu);
          acc[ms][0] = __builtin_amdgcn_mfma_f32_32x32x16_bf16(av, b0, acc[ms][0], 0, 0, 0);
          acc[ms][1] = __builtin_amdgcn_mfma_f32_32x32x16_bf16(av, b1, acc[ms][1], 0, 0, 0);
        }
      }
    } else if (it == 128) {
      // U1 term: A-fragment = h1 (m-major)
#pragma unroll
      for (int c = 0; c < 8; ++c) {
        uint4v bv0 = *reinterpret_cast<const uint4v*>(bit + c * 1024);
        uint4v bv1 = *reinterpret_cast<const uint4v*>(bit + 8192 + c * 1024);
        bf16x8 b0 = __builtin_bit_cast(bf16x8, bv0);
        bf16x8 b1 = __builtin_bit_cast(bf16x8, bv1);
#pragma unroll
        for (int ms = 0; ms < 2; ++ms) {
          bf16x8 a = *reinterpret_cast<const bf16x8*>(
              h1bf + (size_t)(mbase + ms * 32 + l31) * HD + c * 16 + oct * 8);
          acc[ms][0] = __builtin_amdgcn_mfma_f32_32x32x16_bf16(a, b0, acc[ms][0], 0, 0, 0);
          acc[ms][1] = __builtin_amdgcn_mfma_f32_32x32x16_bf16(a, b1, acc[ms][1], 0, 0, 0);
        }
      }
    } else {
      // U2 term: A-fragment = h2 (resident)
#pragma unroll
      for (int c = 0; c < 8; ++c) {
        uint4v bv0 = *reinterpret_cast<const uint4v*>(bit + c * 1024);
        uint4v bv1 = *reinterpret_cast<const uint4v*>(bit + 8192 + c * 1024);
        bf16x8 b0 = __builtin_bit_cast(bf16x8, bv0);
        bf16x8 b1 = __builtin_bit_cast(bf16x8, bv1);
#pragma unroll
        for (int ms = 0; ms < 2; ++ms) {
          bf16x8 a = __builtin_bit_cast(bf16x8, h2u[ms][c]);
          acc[ms][0] = __builtin_amdgcn_mfma_f32_32x32x16_bf16(a, b0, acc[ms][0], 0, 0, 0);
          acc[ms][1] = __builtin_amdgcn_mfma_f32_32x32x16_bf16(a, b1, acc[ms][1], 0, 0, 0);
        }
      }
    }
  }

  // epilogue: plain stores to this ks's partial buffer (no atomics, no contention).
  // C/D: col = lane&31, row = (reg&3) + 8*(reg>>2) + 4*oct
  float* my = part + (size_t)ks * PART_ELEMS;
#pragma unroll
  for (int ns = 0; ns < 2; ++ns) {
    int col = n0 + nbase_l + ns * 32 + l31;
#pragma unroll
    for (int ms = 0; ms < 2; ++ms) {
#pragma unroll
      for (int r = 0; r < 16; ++r) {
        int row = (r & 3) + 8 * (r >> 2) + 4 * oct;
        int m = mbase + ms * 32 + row;
        my[(size_t)m * NOUT + col] = acc[ms][ns][r];
      }
    }
  }
}

// ---------------- reduce: out = P0 + P1 (bias already in P1) ----------------
__global__ void reduce2(const float* __restrict__ part, float* __restrict__ out) {
  int i = blockIdx.x * 256 + threadIdx.x;          // 1,572,864 float4s
  float4 a = reinterpret_cast<const float4*>(part)[i];
  float4 b = reinterpret_cast<const float4*>(part + PART_ELEMS)[i];
  float4 o;
  o.x = a.x + b.x; o.y = a.y + b.y; o.z = a.z + b.z; o.w = a.w + b.w;
  reinterpret_cast<float4*>(out)[i] = o;
}

extern "C" void kernel_launch(void* const* d_in, const int* in_sizes, int n_in,
                              void* d_out, int out_size, void* d_ws, size_t ws_size,
                              hipStream_t stream) {
  const float* nh  = (const float*)d_in[0];   // (16384, 2, 128)
  const float* A   = (const float*)d_in[1];   // (128, 128, 384)
  const float* U1  = (const float*)d_in[2];   // (384, 128)
  const float* U2  = (const float*)d_in[3];   // (384, 128)
  const float* U2b = (const float*)d_in[4];   // (384,)

  char* ws = (char*)d_ws;
  ushort_t* pk   = (ushort_t*)(ws);                 // 130*98304    = 12,779,520 B
  ushort_t* h1bf = (ushort_t*)(ws + 12779520);      // 16384*128*2 =  4,194,304
  ushort_t* h2bf = (ushort_t*)(ws + 16973824);      //               4,194,304
  ushort_t* h1t  = (ushort_t*)(ws + 21168128);      //               4,194,304
  float*    part = (float*)(ws + 25362432);         // 2*25,165,824 = 50,331,648  (ws total 75.7 MB)

  prep_all<<<dim3(772), 384, 0, stream>>>(A, U1, U2, nh, pk, h1bf, h2bf, h1t);
  gemm_kernel<<<dim3(768), 256, 0, stream>>>(pk, h1bf, h2bf, h1t, U2b, part);
  reduce2<<<dim3(6144), 256, 0, stream>>>(part, (float*)d_out);
}

// Round 9
// 579.417 us; speedup vs baseline: 1.5640x; 1.1083x over previous
//
#include <hip/hip_runtime.h>
#include <hip/hip_bf16.h>

typedef __attribute__((ext_vector_type(8))) short bf16x8;
typedef __attribute__((ext_vector_type(16))) float f32x16;
typedef __attribute__((ext_vector_type(4))) float f32x4;
typedef __attribute__((ext_vector_type(4))) unsigned int uint4v;
typedef unsigned short ushort_t;
typedef unsigned int uint_t;

#define N_NODES 16384
#define HD 128
#define NOUT 384
#define PART_ELEMS 6291456    // 16384*384
// packed B: pk[it][g][c][oct][l31][j]  it:0..129 (128,129 = U1,U2 tails)
//   byte offset = ((it*12+g)*16 + c*2 + oct)*512 + l31*16 + j*2 ; per-it = 98304 B

static __device__ __forceinline__ ushort_t f2bf(float f) {
  __hip_bfloat16 b = __float2bfloat16(f);
  return *reinterpret_cast<ushort_t*>(&b);
}

// ---------------- fused prep (384 threads/block) ----------------
__global__ void prep_all(const float* __restrict__ A, const float* __restrict__ U1,
                         const float* __restrict__ U2, const float* __restrict__ nh,
                         ushort_t* __restrict__ pk, ushort_t* __restrict__ h1,
                         ushort_t* __restrict__ h2, float* __restrict__ h1tf) {
  __shared__ __align__(16) char smem[49152];
  const int b = blockIdx.x;
  const int t = threadIdx.x;

  if (b < 260) {
    short* spk = reinterpret_cast<short*>(smem);
    const int half = b & 1;
    const int gg = t >> 5, ll = t & 31;
    if (b < 256) {
      const int it = b >> 1;
      const size_t krow0 = (size_t)it * 128 + half * 64;
#pragma unroll 4
      for (int kl = 0; kl < 64; ++kl) {
        float v = A[(krow0 + kl) * NOUT + t];
        int cl = kl >> 4, oc = (kl >> 3) & 1, j = kl & 7;
        spk[(gg * 8 + cl * 2 + oc) * 256 + ll * 8 + j] = f2bf(v);
      }
    } else {
      const int u = (b - 256) >> 1;
      const float* U = u ? U2 : U1;
#pragma unroll 4
      for (int kl = 0; kl < 64; ++kl) {
        float v = U[(size_t)t * HD + half * 64 + kl];
        int cl = kl >> 4, oc = (kl >> 3) & 1, j = kl & 7;
        spk[(gg * 8 + cl * 2 + oc) * 256 + ll * 8 + j] = f2bf(v);
      }
    }
    __syncthreads();
    const int it_out = (b < 256) ? (b >> 1) : (128 + ((b - 256) >> 1));
    const int f = t * 64;
    const int g = f >> 11;
    const int inner = f & 2047;
    ushort_t* dst = pk + (size_t)it_out * 49152 + g * 4096 + half * 2048 + inner;
    const uint4* src = reinterpret_cast<const uint4*>(spk + f);
    uint4* d4 = reinterpret_cast<uint4*>(dst);
#pragma unroll
    for (int q = 0; q < 8; ++q) d4[q] = src[q];
  } else {
    if (t < 256) {
      float (*sm)[65] = reinterpret_cast<float(*)[65]>(smem);
      const int g = b - 260;            // 0..511
      const int mt = g & 255, jt = g >> 8;
      const int tx = t & 63, ty = t >> 6;
      const int m0 = mt * 64, j0 = jt * 64;
#pragma unroll
      for (int s = 0; s < 16; ++s) {
        int mm = ty + s * 4;
        float f1 = nh[(size_t)(m0 + mm) * 256 + j0 + tx];
        float f2 = nh[(size_t)(m0 + mm) * 256 + 128 + j0 + tx];
        h1[(size_t)(m0 + mm) * HD + j0 + tx] = f2bf(f1);
        h2[(size_t)(m0 + mm) * HD + j0 + tx] = f2bf(f2);
        sm[mm][tx] = f1;
      }
      __syncthreads();
#pragma unroll
      for (int s = 0; s < 16; ++s) {
        int jj = ty + s * 4;
        h1tf[(size_t)(j0 + jj) * N_NODES + m0 + tx] = sm[tx][jj];   // f32 transposed h1
      }
    }
  }
}

// ---------------- main GEMM: barrier-free, LDS-free, synthesis-free ----------------
// out[m,n] = sum_i h1[m,i] * (sum_j h2[m,j] * B_i[j,n]) + U-tails + bias.
// Per slice i: P[ms] = 8-step MFMA chain with A = resident h2 fragments (constant),
// then acc[ms][ns][r] += h1[m(r), i] * P[ms][r]  (h1 in f32, C-layout broadcast loads).
// grid = 128 Mt x 3 Nt x 2 ks. ks=0: it 0..63 -> part[0]; ks=1: it 64..129 (+bias) -> part[1].
__global__ __launch_bounds__(256)
void gemm_kernel(const ushort_t* __restrict__ pk, const ushort_t* __restrict__ h1bf,
                 const ushort_t* __restrict__ h2bf, const float* __restrict__ h1tf,
                 const float* __restrict__ u2b, float* __restrict__ part) {
  const int tid = threadIdx.x;
  const int bid = blockIdx.x;
  const int ks = bid & 1;
  const int mn = bid >> 1;
  const int Nt = mn % 3, Mt = mn / 3;
  const int n0 = Nt * 128, m0 = Mt * 128;
  const int lane = tid & 63, wv = tid >> 6;
  const int l31 = lane & 31, oct = lane >> 5;
  const int wm = wv >> 1, wn = wv & 1;           // 2x2 wave grid
  const int mbase = m0 + wm * 64;
  const int nbase_l = wn * 64;

  const int k_begin = ks ? 64 : 0;
  const int k_end   = ks ? 130 : 64;

  const int g0 = Nt * 4 + wn * 2;
  const char* pkb = reinterpret_cast<const char*>(pk);
  const char* b0base = pkb + (size_t)(g0 * 16 + oct) * 512 + (size_t)l31 * 16;

  // resident h2 A-fragments: rows mbase+ms*32+l31, k2 = c*16 + oct*8 + [0..8)
  uint4v h2u[2][8];
#pragma unroll
  for (int ms = 0; ms < 2; ++ms) {
    const ushort_t* hp = h2bf + (size_t)(mbase + ms * 32 + l31) * HD + oct * 8;
#pragma unroll
    for (int c = 0; c < 8; ++c)
      h2u[ms][c] = *reinterpret_cast<const uint4v*>(hp + c * 16);
  }

  // acc init: bias on ks==1 (col = lane&31 identical for all 16 regs), else 0
  f32x16 acc[2][2];
  {
    float bb0 = ks ? u2b[n0 + nbase_l + l31] : 0.0f;
    float bb1 = ks ? u2b[n0 + nbase_l + 32 + l31] : 0.0f;
#pragma unroll
    for (int ms = 0; ms < 2; ++ms) {
      acc[ms][0] = (f32x16)(bb0);
      acc[ms][1] = (f32x16)(bb1);
    }
  }

  const f32x16 vzero = (f32x16)(0.0f);

  for (int it = k_begin; it < k_end; ++it) {
    const char* bit = b0base + (size_t)it * 98304;
    if (it < 128) {
      // h1 in C-layout, f32: h1q[ms][q][r&3] = h1[mbase+ms*32+4*oct+8*q+(r&3)][it]
      f32x4 h1q[2][4];
#pragma unroll
      for (int ms = 0; ms < 2; ++ms)
#pragma unroll
        for (int q = 0; q < 4; ++q)
          h1q[ms][q] = *reinterpret_cast<const f32x4*>(
              h1tf + (size_t)it * N_NODES + mbase + ms * 32 + 4 * oct + 8 * q);

#pragma unroll
      for (int ns = 0; ns < 2; ++ns) {
        uint4v bb[8];
#pragma unroll
        for (int c = 0; c < 8; ++c)
          bb[c] = *reinterpret_cast<const uint4v*>(bit + ns * 8192 + c * 1024);

        f32x16 P0 = vzero, P1 = vzero;
#pragma unroll
        for (int c = 0; c < 8; ++c) {
          bf16x8 bfr = __builtin_bit_cast(bf16x8, bb[c]);
          P0 = __builtin_amdgcn_mfma_f32_32x32x16_bf16(
              __builtin_bit_cast(bf16x8, h2u[0][c]), bfr, P0, 0, 0, 0);
          P1 = __builtin_amdgcn_mfma_f32_32x32x16_bf16(
              __builtin_bit_cast(bf16x8, h2u[1][c]), bfr, P1, 0, 0, 0);
        }
#pragma unroll
        for (int r = 0; r < 16; ++r) {
          acc[0][ns][r] += h1q[0][r >> 2][r & 3] * P0[r];
          acc[1][ns][r] += h1q[1][r >> 2][r & 3] * P1[r];
        }
      }
    } else if (it == 128) {
      // U1 term: A-fragment = h1 (m-major), MFMA straight into acc
#pragma unroll
      for (int c = 0; c < 8; ++c) {
        uint4v bv0 = *reinterpret_cast<const uint4v*>(bit + c * 1024);
        uint4v bv1 = *reinterpret_cast<const uint4v*>(bit + 8192 + c * 1024);
        bf16x8 b0 = __builtin_bit_cast(bf16x8, bv0);
        bf16x8 b1 = __builtin_bit_cast(bf16x8, bv1);
#pragma unroll
        for (int ms = 0; ms < 2; ++ms) {
          bf16x8 a = *reinterpret_cast<const bf16x8*>(
              h1bf + (size_t)(mbase + ms * 32 + l31) * HD + c * 16 + oct * 8);
          acc[ms][0] = __builtin_amdgcn_mfma_f32_32x32x16_bf16(a, b0, acc[ms][0], 0, 0, 0);
          acc[ms][1] = __builtin_amdgcn_mfma_f32_32x32x16_bf16(a, b1, acc[ms][1], 0, 0, 0);
        }
      }
    } else {
      // U2 term: A-fragment = h2 (resident)
#pragma unroll
      for (int c = 0; c < 8; ++c) {
        uint4v bv0 = *reinterpret_cast<const uint4v*>(bit + c * 1024);
        uint4v bv1 = *reinterpret_cast<const uint4v*>(bit + 8192 + c * 1024);
        bf16x8 b0 = __builtin_bit_cast(bf16x8, bv0);
        bf16x8 b1 = __builtin_bit_cast(bf16x8, bv1);
#pragma unroll
        for (int ms = 0; ms < 2; ++ms) {
          bf16x8 a = __builtin_bit_cast(bf16x8, h2u[ms][c]);
          acc[ms][0] = __builtin_amdgcn_mfma_f32_32x32x16_bf16(a, b0, acc[ms][0], 0, 0, 0);
          acc[ms][1] = __builtin_amdgcn_mfma_f32_32x32x16_bf16(a, b1, acc[ms][1], 0, 0, 0);
        }
      }
    }
  }

  // epilogue: plain stores to this ks's partial buffer.
  // C/D: col = lane&31, row = (reg&3) + 8*(reg>>2) + 4*oct
  float* my = part + (size_t)ks * PART_ELEMS;
#pragma unroll
  for (int ns = 0; ns < 2; ++ns) {
    int col = n0 + nbase_l + ns * 32 + l31;
#pragma unroll
    for (int ms = 0; ms < 2; ++ms) {
#pragma unroll
      for (int r = 0; r < 16; ++r) {
        int row = (r & 3) + 8 * (r >> 2) + 4 * oct;
        int m = mbase + ms * 32 + row;
        my[(size_t)m * NOUT + col] = acc[ms][ns][r];
      }
    }
  }
}

// ---------------- reduce: out = P0 + P1 (bias already in P1) ----------------
__global__ void reduce2(const float* __restrict__ part, float* __restrict__ out) {
  int i = blockIdx.x * 256 + threadIdx.x;          // 1,572,864 float4s
  float4 a = reinterpret_cast<const float4*>(part)[i];
  float4 b = reinterpret_cast<const float4*>(part + PART_ELEMS)[i];
  float4 o;
  o.x = a.x + b.x; o.y = a.y + b.y; o.z = a.z + b.z; o.w = a.w + b.w;
  reinterpret_cast<float4*>(out)[i] = o;
}

extern "C" void kernel_launch(void* const* d_in, const int* in_sizes, int n_in,
                              void* d_out, int out_size, void* d_ws, size_t ws_size,
                              hipStream_t stream) {
  const float* nh  = (const float*)d_in[0];   // (16384, 2, 128)
  const float* A   = (const float*)d_in[1];   // (128, 128, 384)
  const float* U1  = (const float*)d_in[2];   // (384, 128)
  const float* U2  = (const float*)d_in[3];   // (384, 128)
  const float* U2b = (const float*)d_in[4];   // (384,)

  char* ws = (char*)d_ws;
  ushort_t* pk   = (ushort_t*)(ws);                 // 130*98304    = 12,779,520 B
  ushort_t* h1bf = (ushort_t*)(ws + 12779520);      // 16384*128*2 =  4,194,304
  ushort_t* h2bf = (ushort_t*)(ws + 16973824);      //               4,194,304
  float*    h1tf = (float*)(ws + 21168128);         // 128*16384*4 =  8,388,608
  float*    part = (float*)(ws + 29556736);         // 2*25,165,824 = 50,331,648  (total ~79.9 MB)

  prep_all<<<dim3(772), 384, 0, stream>>>(A, U1, U2, nh, pk, h1bf, h2bf, h1tf);
  gemm_kernel<<<dim3(768), 256, 0, stream>>>(pk, h1bf, h2bf, h1tf, U2b, part);
  reduce2<<<dim3(6144), 256, 0, stream>>>(part, (float*)d_out);
}